// Round 3
// baseline (646.275 us; speedup 1.0000x reference)
//
#include <hip/hip_runtime.h>

#define NF   20480
#define NACC 128
#define BATCH 4096
#define MAXI 512    // nnz/row ~ Binom(20480,0.0015): mean 31, max over 8192 rows ~ 65

typedef unsigned int uvec4 __attribute__((ext_vector_type(4)));   // native vector: OK for nontemporal builtins

// acc_w [128][20480] f32 -> accT [20480][128] f32 (feature's 128 channels contiguous, 512 B)
__global__ __launch_bounds__(256) void transpose_accw(const float* __restrict__ acc_w,
                                                      float* __restrict__ accT) {
    __shared__ float tile[NACC][33];            // [channel][feature_local], padded
    const int t  = threadIdx.x;
    const int f0 = blockIdx.x * 32;             // 32 features per block, grid = 640
    const int fl = t & 31;
    const int cr = t >> 5;                      // 0..7
    #pragma unroll
    for (int i = 0; i < 16; ++i) {
        int cc = i * 8 + cr;
        tile[cc][fl] = acc_w[(size_t)cc * NF + f0 + fl];   // coalesced along features
    }
    __syncthreads();
    const int c  = t & 127;
    const int fr = t >> 7;                      // 0..1
    #pragma unroll
    for (int i = 0; i < 16; ++i) {
        int ff = i * 2 + fr;
        accT[(size_t)(f0 + ff) * NACC + c] = tile[c][ff];  // coalesced along channels
    }
}

__global__ __launch_bounds__(256) void nnue_main(
    const float* __restrict__ white,
    const float* __restrict__ black,
    const float* __restrict__ psqt_w,   // [2][NF]
    const float* __restrict__ accT,     // [NF][128] (transposed), valid iff useT
    const float* __restrict__ acc_w,    // [128][NF] fallback
    const float* __restrict__ acc_b,    // [128]
    const float* __restrict__ out_w,    // [2][128]
    float* __restrict__ out,            // [BATCH][2]
    int useT)
{
    __shared__ int   s_cnt;
    __shared__ int   s_idx[MAXI];
    __shared__ float s_red[8];
    __shared__ float s_ps[2];

    const int t = threadIdx.x;
    const int b = blockIdx.x;

    float bias = 0.f, ow0 = 0.f, ow1 = 0.f;
    if (t < NACC) {
        bias = acc_b[t];
        ow0  = out_w[t];
        ow1  = out_w[NACC + t];
    }

    float res0 = 0.f, res1 = 0.f;   // only thread 0's copy is meaningful

    for (int side = 0; side < 2; ++side) {
        const float* X = (side ? black : white) + (size_t)b * NF;
        const uvec4* Xv = (const uvec4*)X;    // row is 81920-B aligned; 4 floats/vec

        if (t == 0) s_cnt = 0;
        __syncthreads();

        // ---- scan 20480 f32 = 5120 uvec4; 256 threads x 20 iters, coalesced, nontemporal ----
        #pragma unroll
        for (int i = 0; i < 20; ++i) {
            int v = i * 256 + t;
            uvec4 u = __builtin_nontemporal_load(&Xv[v]);
            if (u.x | u.y | u.z | u.w) {     // rare (values are 0.0f or 1.0f)
                int base = v * 4;
                if (u.x) { int p = atomicAdd(&s_cnt, 1); if (p < MAXI) s_idx[p] = base + 0; }
                if (u.y) { int p = atomicAdd(&s_cnt, 1); if (p < MAXI) s_idx[p] = base + 1; }
                if (u.z) { int p = atomicAdd(&s_cnt, 1); if (p < MAXI) s_idx[p] = base + 2; }
                if (u.w) { int p = atomicAdd(&s_cnt, 1); if (p < MAXI) s_idx[p] = base + 3; }
            }
        }
        __syncthreads();
        const int n = min(s_cnt, MAXI);

        // ---- gather + accumulate ----
        float acc = 0.f, ps = 0.f;
        if (t < NACC) {
            if (useT) {
                for (int i = 0; i < n; ++i)
                    acc += accT[(size_t)s_idx[i] * NACC + t];   // 512 B coalesced / feature
            } else {
                for (int i = 0; i < n; ++i)
                    acc += acc_w[(size_t)t * NF + s_idx[i]];    // uncoalesced fallback
            }
        } else if (t < NACC + 2) {
            const int s = t - NACC;
            for (int i = 0; i < n; ++i)
                ps += psqt_w[(size_t)s * NF + s_idx[i]];
        }

        // ---- CReLU + out_w dot, reduce across threads 0..127 ----
        float h = acc + bias;
        h = fminf(fmaxf(h, 0.f), 1.f);
        float p0 = (t < NACC) ? h * ow0 : 0.f;
        float p1 = (t < NACC) ? h * ow1 : 0.f;
        #pragma unroll
        for (int off = 32; off > 0; off >>= 1) {
            p0 += __shfl_down(p0, off, 64);
            p1 += __shfl_down(p1, off, 64);
        }
        const int wave = t >> 6;
        if ((t & 63) == 0) { s_red[wave * 2] = p0; s_red[wave * 2 + 1] = p1; }
        if (t == NACC)     s_ps[0] = ps;
        if (t == NACC + 1) s_ps[1] = ps;
        __syncthreads();

        if (t == 0) {
            float pos0 = s_red[0] + s_red[2];   // waves 0,1 hold threads 0..127
            float pos1 = s_red[1] + s_red[3];
            float sgn  = side ? -1.f : 1.f;
            res0 += sgn * (pos0 + s_ps[0]);
            res1 += sgn * (pos1 + s_ps[1]);
        }
        __syncthreads();   // protect s_red/s_ps/s_cnt before next side
    }

    if (t == 0) {
        out[(size_t)b * 2 + 0] = res0;
        out[(size_t)b * 2 + 1] = res1;
    }
}

extern "C" void kernel_launch(void* const* d_in, const int* in_sizes, int n_in,
                              void* d_out, int out_size, void* d_ws, size_t ws_size,
                              hipStream_t stream) {
    const float* white  = (const float*)d_in[0];
    const float* black  = (const float*)d_in[1];
    const float* psqt_w = (const float*)d_in[2];
    const float* acc_w  = (const float*)d_in[3];
    const float* acc_b  = (const float*)d_in[4];
    const float* out_w  = (const float*)d_in[5];
    float* out = (float*)d_out;

    float* accT = (float*)d_ws;
    const size_t need = (size_t)NF * NACC * sizeof(float);
    const int useT = (ws_size >= need) ? 1 : 0;

    if (useT) {
        transpose_accw<<<NF / 32, 256, 0, stream>>>(acc_w, accT);
    }
    nnue_main<<<BATCH, 256, 0, stream>>>(white, black, psqt_w, accT, acc_w,
                                         acc_b, out_w, out, useT);
}